// Round 11
// baseline (1198.095 us; speedup 1.0000x reference)
//
#include <hip/hip_runtime.h>
#include <hip/hip_bf16.h>
#include <math.h>

// Problem dims (fixed by reference)
#define B 32
#define S 256
#define H 768
#define KG 200
#define KGP 224      // KG padded to x32
#define FF 3072
#define LH 128
#define D 968        // H + KG
#define DP 1024      // D padded to multiple of 32
#define NT 11
#define G4 512       // 4*LH
#define START_TAG 9
#define END_TAG 10
#define M_TOK 8192   // B*S
#define L2E 1.4426950408889634f

typedef __attribute__((ext_vector_type(8))) short short8;
typedef __attribute__((ext_vector_type(4))) float f32x4;

// ---------------------------------------------------------------------------
__device__ __forceinline__ void gl_lds16(const void* gptr, void* lptr) {
    __builtin_amdgcn_global_load_lds(
        (const __attribute__((address_space(1))) void*)gptr,
        (__attribute__((address_space(3))) void*)lptr,
        16, 0, 0);
}

// LDS-only barrier (lgkmcnt(0); vmcnt/expcnt unconstrained).
__device__ __forceinline__ void barrier_lds() {
    __builtin_amdgcn_sched_barrier(0);
    __builtin_amdgcn_s_waitcnt(0xC07F);
    __builtin_amdgcn_s_barrier();
    __builtin_amdgcn_sched_barrier(0);
}

__device__ __forceinline__ float frcp(float x) { return __builtin_amdgcn_rcpf(x); }
// RAW hardware v_exp_f32 (exp2). exp2f() w/o -ffast-math lowers to the slow
// __ocml path (round-9 regression); the builtin is the bare instruction.
__device__ __forceinline__ float e2(float x) { return __builtin_amdgcn_exp2f(x); }

__device__ __forceinline__ float fsigmoid(float x) {
    return frcp(1.f + __expf(-x));
}
__device__ __forceinline__ float ftanh(float x) {
    return 1.f - 2.f * frcp(__expf(2.f * x) + 1.f);
}

// ---------------------------------------------------------------------------
// kg slice cast: Akg (M_TOK, KGP) bf16 from in_emb cols H..D, zero pad.
__global__ __launch_bounds__(256) void castpad_kg_kernel(
    const float* __restrict__ in, __hip_bfloat16* __restrict__ Akg)
{
    size_t idx = (size_t)blockIdx.x * 256 + threadIdx.x;
    if (idx >= (size_t)M_TOK * KGP) return;
    int k = (int)(idx % KGP);
    size_t tok = idx / KGP;
    float v = (k < KG) ? in[tok * D + H + k] : 0.f;
    Akg[idx] = __float2bfloat16(v);
}

// ---------------------------------------------------------------------------
// LayerNorm + tanh + W2-dot per token; one wave per token (h in bf16).
__global__ __launch_bounds__(256) void ln_score_kernel(
    const __hip_bfloat16* __restrict__ h16,    // (M_TOK, H)
    const float* __restrict__ ln_g, const float* __restrict__ ln_b,
    const float* __restrict__ W2, const float* __restrict__ b2,
    float* __restrict__ scores)
{
    int wave = threadIdx.x >> 6, lane = threadIdx.x & 63;
    int tok = blockIdx.x * 4 + wave;
    const __hip_bfloat16* hp = h16 + (size_t)tok * H;
    float v[12], s1 = 0.f, s2 = 0.f;
#pragma unroll
    for (int i = 0; i < 12; ++i) {
        v[i] = __bfloat162float(hp[i * 64 + lane]);
        s1 += v[i]; s2 += v[i] * v[i];
    }
#pragma unroll
    for (int o = 32; o > 0; o >>= 1) {
        s1 += __shfl_xor(s1, o, 64);
        s2 += __shfl_xor(s2, o, 64);
    }
    float mu = s1 * (1.f / H);
    float var = s2 * (1.f / H) - mu * mu;
    float rstd = rsqrtf(var + 1e-5f);
    float sc = 0.f;
#pragma unroll
    for (int i = 0; i < 12; ++i) {
        int cidx = i * 64 + lane;
        sc += ftanh((v[i] - mu) * rstd * ln_g[cidx] + ln_b[cidx]) * W2[cidx];
    }
#pragma unroll
    for (int o = 32; o > 0; o >>= 1) sc += __shfl_xor(sc, o, 64);
    if (lane == 0) scores[tok] = sc + b2[0];
}

// ---------------------------------------------------------------------------
__global__ __launch_bounds__(256) void softmax_kernel(
    const float* __restrict__ scores, float* __restrict__ attw)
{
    int b = blockIdx.x, tid = threadIdx.x;
    __shared__ float red[256];
    float v = scores[b * S + tid];
    red[tid] = v; __syncthreads();
    for (int st = 128; st > 0; st >>= 1) {
        if (tid < st) red[tid] = fmaxf(red[tid], red[tid + st]);
        __syncthreads();
    }
    float m = red[0]; __syncthreads();
    float e = expf(v - m);
    red[tid] = e; __syncthreads();
    for (int st = 128; st > 0; st >>= 1) {
        if (tid < st) red[tid] += red[tid + st];
        __syncthreads();
    }
    attw[b * S + tid] = e / red[0];
}

// ---------------------------------------------------------------------------
// combined = [bert, kg*(1+attw)] -> bf16 K-padded (also the FF2 residual).
__global__ __launch_bounds__(256) void combine2_kernel(
    const float* __restrict__ in, const float* __restrict__ attw,
    __hip_bfloat16* __restrict__ Ab)
{
    size_t idx = (size_t)blockIdx.x * 256 + threadIdx.x;
    if (idx >= (size_t)M_TOK * DP) return;
    int d = (int)(idx & (DP - 1));
    size_t tok = idx >> 10;
    float v = 0.f;
    if (d < D) {
        v = in[tok * D + d];
        if (d >= H) v *= (1.f + attw[tok]);
    }
    Ab[idx] = __float2bfloat16(v);
}

// ---------------------------------------------------------------------------
// ONE-SHOT weight prep: all bf16 casts/pads/gate-scales in a single launch.
#define N_FF1  (FF * DP)            // 3,145,728
#define N_FF2  (DP * FF)            // 3,145,728
#define N_W0   (512 * DP)           // per half
#define N_W1   (512 * 256)
#define N_WHH  65536
#define PREP_TOTAL (N_FF1 + N_FF2 + 2*N_W0 + 2*N_W1 + 4*N_WHH + 2048 + 32768 + H*KGP)
__global__ __launch_bounds__(256) void prep_all_kernel(
    const float* __restrict__ ff_W1, const float* __restrict__ ff_W2,
    const float* __restrict__ Wih0f, const float* __restrict__ Wih0b,
    const float* __restrict__ Wih1f, const float* __restrict__ Wih1b,
    const float* __restrict__ Whh0f, const float* __restrict__ Whh0b,
    const float* __restrict__ Whh1f, const float* __restrict__ Whh1b,
    const float* __restrict__ b0f, const float* __restrict__ b0b,
    const float* __restrict__ b1f, const float* __restrict__ b1b,
    const float* __restrict__ cls_W, const float* __restrict__ kg_W1,
    __hip_bfloat16* __restrict__ Wbff1, __hip_bfloat16* __restrict__ Wbff2,
    __hip_bfloat16* __restrict__ Wb0, __hip_bfloat16* __restrict__ Wb1,
    __hip_bfloat16* __restrict__ Whb0f, __hip_bfloat16* __restrict__ Whb0b,
    __hip_bfloat16* __restrict__ Whb1f, __hip_bfloat16* __restrict__ Whb1b,
    float* __restrict__ sb0, float* __restrict__ sb1,
    __hip_bfloat16* __restrict__ Wbcls, __hip_bfloat16* __restrict__ Wbkg1)
{
    const float SG[4] = { -L2E, -L2E, 2.f * L2E, -L2E };
    size_t idx = (size_t)blockIdx.x * 256 + threadIdx.x;
    if (idx < N_FF1) {                        // ff_W1 (FF,D)->(FF,DP)
        int n = (int)(idx >> 10), k = (int)(idx & (DP - 1));
        Wbff1[idx] = __float2bfloat16(k < D ? ff_W1[(size_t)n * D + k] : 0.f);
        return;
    }
    idx -= N_FF1;
    if (idx < N_FF2) {                        // ff_W2 (D,FF)->(DP,FF)
        int n = (int)(idx / FF), k = (int)(idx % FF);
        Wbff2[idx] = __float2bfloat16(n < D ? ff_W2[(size_t)n * FF + k] : 0.f);
        return;
    }
    idx -= N_FF2;
    if (idx < 2 * N_W0) {                     // Wih0 f|b stacked, gate-scaled
        int half = (int)(idx / N_W0); size_t i = idx % N_W0;
        int n = (int)(i >> 10), k = (int)(i & (DP - 1));
        const float* src = half ? Wih0b : Wih0f;
        float v = (k < D) ? src[(size_t)n * D + k] * SG[(n >> 7) & 3] : 0.f;
        Wb0[idx] = __float2bfloat16(v);
        return;
    }
    idx -= 2 * N_W0;
    if (idx < 2 * N_W1) {                     // Wih1 f|b stacked, gate-scaled
        int half = (int)(idx / N_W1); size_t i = idx % N_W1;
        int n = (int)(i >> 8);
        const float* src = half ? Wih1b : Wih1f;
        float v = src[i] * SG[(n >> 7) & 3];
        Wb1[idx] = __float2bfloat16(v);
        return;
    }
    idx -= 2 * N_W1;
    if (idx < 4 * N_WHH) {                    // Whh x4, gate-scaled
        int seg = (int)(idx >> 16), i = (int)(idx & (N_WHH - 1));
        float s = SG[i >> 14];
        const float* srcs[4] = { Whh0f, Whh0b, Whh1f, Whh1b };
        __hip_bfloat16* dsts[4] = { Whb0f, Whb0b, Whb1f, Whb1b };
        dsts[seg][i] = __float2bfloat16(srcs[seg][i] * s);
        return;
    }
    idx -= 4 * N_WHH;
    if (idx < 1024) {
        int n = (int)idx;
        sb0[n] = ((n < 512) ? b0f[n] : b0b[n - 512]) * SG[(n >> 7) & 3];
        return;
    }
    idx -= 1024;
    if (idx < 1024) {
        int n = (int)idx;
        sb1[n] = ((n < 512) ? b1f[n] : b1b[n - 512]) * SG[(n >> 7) & 3];
        return;
    }
    idx -= 1024;
    if (idx < 32768) {
        int n = (int)(idx >> 8), k = (int)(idx & 255);
        Wbcls[idx] = __float2bfloat16(n < NT ? cls_W[n * 256 + k] : 0.f);
        return;
    }
    idx -= 32768;
    if (idx < (size_t)H * KGP) {
        int n = (int)(idx / KGP), k = (int)(idx % KGP);
        Wbkg1[idx] = __float2bfloat16(k < KG ? kg_W1[(size_t)n * KG + k] : 0.f);
    }
}

// ---------------------------------------------------------------------------
// bf16 MFMA GEMM: C(M,Np) = act(A(M,Kp) @ W(Np,Kp)^T + bias) [+ res].
// flags: bit0 relu; bit1 bf16 out; bit2 LSTM gate-interleave fp32 store;
// bit3 compact fp32 store stride N_real; bit4 res is bf16.
__global__ __launch_bounds__(256) void mfma_gemm(
    const __hip_bfloat16* __restrict__ A,
    const __hip_bfloat16* __restrict__ Wb,
    const float* __restrict__ bias,
    const void* __restrict__ res, int res_ld, size_t half_stride,
    void* __restrict__ Cout,
    int Np, int Kp, int N_real, int flags)
{
    __shared__ short As[128 * 32];
    __shared__ short Bs[128 * 32];
    const int tid  = threadIdx.x;
    const int wave = tid >> 6;
    const int lane = tid & 63;
    const int bm = blockIdx.y * 128, bn = blockIdx.x * 128;
    const int sr = lane >> 2;
    const int sc = (lane & 3) * 8;
    const int fr = lane & 15;
    const int fq = lane >> 4;
    const int wm = (wave >> 1) * 64, wn = (wave & 1) * 64;

    f32x4 acc[4][4];
#pragma unroll
    for (int i = 0; i < 4; ++i)
#pragma unroll
        for (int j = 0; j < 4; ++j) acc[i][j] = (f32x4){0.f, 0.f, 0.f, 0.f};

    const __hip_bfloat16* ga0 = A  + (size_t)(bm + wave * 32      + sr) * Kp + sc;
    const __hip_bfloat16* ga1 = A  + (size_t)(bm + wave * 32 + 16 + sr) * Kp + sc;
    const __hip_bfloat16* gb0 = Wb + (size_t)(bn + wave * 32      + sr) * Kp + sc;
    const __hip_bfloat16* gb1 = Wb + (size_t)(bn + wave * 32 + 16 + sr) * Kp + sc;
    short* lA0 = &As[(wave * 2 + 0) * 512];
    short* lA1 = &As[(wave * 2 + 1) * 512];
    short* lB0 = &Bs[(wave * 2 + 0) * 512];
    short* lB1 = &Bs[(wave * 2 + 1) * 512];

    for (int k0 = 0; k0 < Kp; k0 += 32) {
        gl_lds16(ga0 + k0, lA0);
        gl_lds16(ga1 + k0, lA1);
        gl_lds16(gb0 + k0, lB0);
        gl_lds16(gb1 + k0, lB1);
        __syncthreads();

        short8 af[4], bfr[4];
#pragma unroll
        for (int mi = 0; mi < 4; ++mi)
            af[mi] = *(const short8*)&As[(wm + mi * 16 + fr) * 32 + fq * 8];
#pragma unroll
        for (int ni = 0; ni < 4; ++ni)
            bfr[ni] = *(const short8*)&Bs[(wn + ni * 16 + fr) * 32 + fq * 8];
#pragma unroll
        for (int mi = 0; mi < 4; ++mi)
#pragma unroll
            for (int ni = 0; ni < 4; ++ni)
                acc[mi][ni] = __builtin_amdgcn_mfma_f32_16x16x32_bf16(
                    af[mi], bfr[ni], acc[mi][ni], 0, 0, 0);
        __syncthreads();
    }

    const bool relu = flags & 1;
    const bool obf  = flags & 2;
    const bool gate = flags & 4;
    const bool cmp  = flags & 8;
    const bool rbf  = flags & 16;
#pragma unroll
    for (int mi = 0; mi < 4; ++mi) {
#pragma unroll
        for (int ni = 0; ni < 4; ++ni) {
#pragma unroll
            for (int r = 0; r < 4; ++r) {
                int m = bm + wm + mi * 16 + fq * 4 + r;
                int n = bn + wn + ni * 16 + fr;
                float v = acc[mi][ni][r];
                if (n < N_real) {
                    v += bias[n];
                    if (relu) v = fmaxf(v, 0.f);
                    if (res) {
                        if (rbf)
                            v += __bfloat162float(
                                ((const __hip_bfloat16*)res)[(size_t)m * res_ld + n]);
                        else
                            v += ((const float*)res)[(size_t)m * res_ld + n];
                    }
                } else {
                    v = 0.f;
                }
                if (gate) {
                    ((float*)Cout)[(size_t)m * 512 + ((n & 127) << 2)
                                   + ((n >> 7) & 3) + (size_t)(n >> 9) * half_stride] = v;
                } else if (cmp) {
                    if (n < N_real)
                        ((float*)Cout)[(size_t)m * N_real + n] = v;
                } else if (obf) {
                    ((__hip_bfloat16*)Cout)[(size_t)m * Np + n] = __float2bfloat16(v);
                } else {
                    ((float*)Cout)[(size_t)m * Np + n] = v;
                }
            }
        }
    }
}

// ---------------------------------------------------------------------------
// Batched MFMA LSTM recurrence, 1024 threads (16 waves = 4/SIMD).
// Unrolled x2 with STATIC ping-pong LDS banks (no runtime LDS addressing),
// running pointers for pre-loads and out-stores (constant bumps), guard-free
// prefetch (1-step overrun lands in adjacent valid workspace), uniform-branch
// row-group select. Gates: 5 raw v_exp + 3 v_rcp per h, log2e prescaled into
// weights/biases.
__global__ __launch_bounds__(1024, 4) void lstm_mfma_kernel(
    const float* __restrict__ pre_f, const float* __restrict__ pre_b,
    const __hip_bfloat16* __restrict__ whh_f,
    const __hip_bfloat16* __restrict__ whh_b,
    __hip_bfloat16* __restrict__ out)   // (B,S,2*LH) bf16
{
    const int dir = blockIdx.x >> 1;
    const int s0  = (blockIdx.x & 1) * 16;
    const float* pre = dir ? pre_b : pre_f;
    const __hip_bfloat16* whh = dir ? whh_b : whh_f;

    const int tid  = threadIdx.x;
    const int w16  = tid >> 6;
    const int grp  = __builtin_amdgcn_readfirstlane(w16 >> 3);  // wave-uniform
    const int w8   = w16 & 7;
    const int lane = tid & 63;
    const int l15  = lane & 15;
    const int q    = lane >> 4;
    const int col  = 16 * w8 + l15;
    const int r0   = grp * 2;

    short8 bf[4][4];
#pragma unroll
    for (int t = 0; t < 4; ++t) {
        const __hip_bfloat16* wrow = whh + (size_t)(t * 128 + col) * LH;
#pragma unroll
        for (int kt = 0; kt < 4; ++kt)
            bf[t][kt] = *(const short8*)(wrow + kt * 32 + q * 8);
    }

    __shared__ __hip_bfloat16 h_lds[2][16][136];
    for (int i = tid; i < 2 * 16 * 136; i += 1024)
        ((__hip_bfloat16*)h_lds)[i] = __float2bfloat16(0.f);

    float c0 = 0.f, c1 = 0.f;

    const int t0 = dir ? (S - 1) : 0;
    const int stepoff = dir ? -G4 : G4;       // pre elements per step
    const int outoff  = dir ? -256 : 256;     // out elements per step
    const int row0 = s0 + 4 * q + r0, row1 = row0 + 1;

    const float* pp0 = pre + ((size_t)row0 * S + t0) * G4 + col * 4;
    const float* pp1 = pre + ((size_t)row1 * S + t0) * G4 + col * 4;
    __hip_bfloat16* op0 = out + ((size_t)row0 * S + t0) * 256 + dir * 128 + col;
    __hip_bfloat16* op1 = out + ((size_t)row1 * S + t0) * 256 + dir * 128 + col;

    float4 pcA0 = *(const float4*)pp0; pp0 += stepoff;
    float4 pcA1 = *(const float4*)pp1; pp1 += stepoff;

    // one step body: read bank RB, write bank WB, consume (g0,g1)
    auto body = [&](const __hip_bfloat16 (&rb)[16][136],
                    __hip_bfloat16 (&wb)[16][136],
                    const float4& g0, const float4& g1) {
        short8 af[4];
#pragma unroll
        for (int kt = 0; kt < 4; ++kt)
            af[kt] = *(const short8*)&rb[l15][kt * 32 + q * 8];

        f32x4 acc[4];
#pragma unroll
        for (int t = 0; t < 4; ++t) {
            acc[t] = (f32x4){0.f, 0.f, 0.f, 0.f};
#pragma unroll
            for (int kt = 0; kt < 4; ++kt)
                acc[t] = __builtin_amdgcn_mfma_f32_16x16x32_bf16(
                    af[kt], bf[t][kt], acc[t], 0, 0, 0);
        }

        float a0[4], a1[4];
        if (grp == 0) {                       // uniform branch (readfirstlane)
#pragma unroll
            for (int t = 0; t < 4; ++t) { a0[t] = acc[t][0]; a1[t] = acc[t][1]; }
        } else {
#pragma unroll
            for (int t = 0; t < 4; ++t) { a0[t] = acc[t][2]; a1[t] = acc[t][3]; }
        }

        float Ei = e2(a0[0] + g0.x);
        float Ef = e2(a0[1] + g0.y);
        float Eg = e2(fminf(a0[2] + g0.z, 80.f));
        float Eo = e2(a0[3] + g0.w);
        float T  = (Eg - 1.f) * frcp((1.f + Ei) * (Eg + 1.f));
        c0 = fmaf(c0, frcp(1.f + Ef), T);
        float E2 = e2(fminf(c0 * (2.f * L2E), 80.f));
        float h0 = (E2 - 1.f) * frcp((1.f + Eo) * (E2 + 1.f));

        Ei = e2(a1[0] + g1.x);
        Ef = e2(a1[1] + g1.y);
        Eg = e2(fminf(a1[2] + g1.z, 80.f));
        Eo = e2(a1[3] + g1.w);
        T  = (Eg - 1.f) * frcp((1.f + Ei) * (Eg + 1.f));
        c1 = fmaf(c1, frcp(1.f + Ef), T);
        E2 = e2(fminf(c1 * (2.f * L2E), 80.f));
        float h1 = (E2 - 1.f) * frcp((1.f + Eo) * (E2 + 1.f));

        __hip_bfloat16 hb0 = __float2bfloat16(h0);
        __hip_bfloat16 hb1 = __float2bfloat16(h1);
        wb[4 * q + r0    ][col] = hb0;
        wb[4 * q + r0 + 1][col] = hb1;
        *op0 = hb0; op0 += outoff;
        *op1 = hb1; op1 += outoff;
    };

    barrier_lds();

    for (int it = 0; it < S / 2; ++it) {
        // even step: bank0 -> bank1, consume A, prefetch B
        float4 pcB0 = *(const float4*)pp0; pp0 += stepoff;
        float4 pcB1 = *(const float4*)pp1; pp1 += stepoff;
        body(h_lds[0], h_lds[1], pcA0, pcA1);
        barrier_lds();
        // odd step: bank1 -> bank0, consume B, prefetch A
        pcA0 = *(const float4*)pp0; pp0 += stepoff;
        pcA1 = *(const float4*)pp1; pp1 += stepoff;
        body(h_lds[1], h_lds[0], pcB0, pcB1);
        barrier_lds();
    }
}

// ---------------------------------------------------------------------------
// CRF NLL per sample — single wave (64 threads), warp-synchronous: shuffle
// reductions, volatile LDS alpha with explicit lgkm waits (no s_barrier).
__global__ __launch_bounds__(64) void crf_kernel(
    const float* __restrict__ em, const int* __restrict__ labels,
    const int* __restrict__ mask, const float* __restrict__ trans,
    float* __restrict__ nll)
{
    int b = blockIdx.x, tid = threadIdx.x;
    __shared__ float tr[NT * NT];
    __shared__ float alpha_s[NT];
    volatile float* alpha = alpha_s;

    for (int i = tid; i < NT * NT; i += 64) tr[i] = trans[i];
    __builtin_amdgcn_s_waitcnt(0xC07F);

    float emit = 0.f, pair = 0.f, lenf = 0.f;
    for (int s = tid; s < S; s += 64) {
        int lab = labels[b * S + s];
        float mf = (float)mask[b * S + s];
        emit += em[(size_t)(b * S + s) * NT + lab] * mf;
        lenf += mf;
        if (s >= 1) {
            int lp = labels[b * S + s - 1];
            pair += tr[lp * NT + lab] * mf;
        }
    }
#pragma unroll
    for (int o = 32; o > 0; o >>= 1) {
        emit += __shfl_xor(emit, o, 64);
        pair += __shfl_xor(pair, o, 64);
        lenf += __shfl_xor(lenf, o, 64);
    }
    float gold = 0.f;
    if (tid == 0) {
        int len_i = (int)(lenf + 0.5f);
        int last = labels[b * S + len_i - 1];
        gold = tr[START_TAG * NT + labels[b * S]] + emit + pair
             + tr[last * NT + END_TAG];
    }
    if (tid < NT) alpha[tid] = tr[START_TAG * NT + tid] + em[(size_t)(b * S) * NT + tid];
    __builtin_amdgcn_s_waitcnt(0xC07F);
    __builtin_amdgcn_wave_barrier();

    float ecur = (tid < NT) ? em[(size_t)(b * S + 1) * NT + tid] : 0.f;
    int   mcur = mask[b * S + 1];

    for (int t = 1; t < S; ++t) {
        float enxt = 0.f; int mnxt = 0;
        if (t + 1 < S) {
            if (tid < NT) enxt = em[(size_t)(b * S + t + 1) * NT + tid];
            mnxt = mask[b * S + t + 1];
        }
        float newv = 0.f;
        if (tid < NT) {
            float aself = alpha[tid];
            float vals[NT];
            float m = -1e30f;
#pragma unroll
            for (int i2 = 0; i2 < NT; ++i2) {
                float v = alpha[i2] + tr[i2 * NT + tid];
                vals[i2] = v;
                m = fmaxf(m, v);
            }
            float ssum = 0.f;
#pragma unroll
            for (int i2 = 0; i2 < NT; ++i2) ssum += __expf(vals[i2] - m);
            newv = m + __logf(ssum) + ecur;
            if (!(mcur > 0)) newv = aself;
        }
        __builtin_amdgcn_wave_barrier();
        if (tid < NT) alpha[tid] = newv;
        __builtin_amdgcn_s_waitcnt(0xC07F);
        __builtin_amdgcn_wave_barrier();
        ecur = enxt; mcur = mnxt;
    }

    if (tid == 0) {
        float m = -1e30f;
        float fin[NT];
        for (int j = 0; j < NT; ++j) {
            fin[j] = alpha[j] + tr[j * NT + END_TAG];
            m = fmaxf(m, fin[j]);
        }
        float ssum = 0.f;
        for (int j = 0; j < NT; ++j) ssum += __expf(fin[j] - m);
        float logZ = m + __logf(ssum);
        nll[b] = logZ - gold;
    }
}

__global__ void mean_kernel(const float* __restrict__ nll, float* __restrict__ out)
{
    if (threadIdx.x == 0) {
        float s = 0.f;
        for (int i = 0; i < B; ++i) s += nll[i];
        out[0] = s / (float)B;
    }
}

// ---------------------------------------------------------------------------
extern "C" void kernel_launch(void* const* d_in, const int* in_sizes, int n_in,
                              void* d_out, int out_size, void* d_ws, size_t ws_size,
                              hipStream_t stream)
{
    const float* in_emb = (const float*)d_in[0];
    const int*   mask   = (const int*)d_in[1];
    const int*   labels = (const int*)d_in[2];
    const float* kg_W1  = (const float*)d_in[3];
    const float* kg_b1  = (const float*)d_in[4];
    const float* ln_g   = (const float*)d_in[5];
    const float* ln_b   = (const float*)d_in[6];
    const float* kg_W2  = (const float*)d_in[7];
    const float* kg_b2  = (const float*)d_in[8];
    const float* ff_W1  = (const float*)d_in[9];
    const float* ff_b1  = (const float*)d_in[10];
    const float* ff_W2  = (const float*)d_in[11];
    const float* ff_b2  = (const float*)d_in[12];
    const float* Wih0f  = (const float*)d_in[13];
    const float* Whh0f  = (const float*)d_in[14];
    const float* b0f    = (const float*)d_in[15];
    const float* Wih0b  = (const float*)d_in[16];
    const float* Whh0b  = (const float*)d_in[17];
    const float* b0b    = (const float*)d_in[18];
    const float* Wih1f  = (const float*)d_in[19];
    const float* Whh1f  = (const float*)d_in[20];
    const float* b1f    = (const float*)d_in[21];
    const float* Wih1b  = (const float*)d_in[22];
    const float* Whh1b  = (const float*)d_in[23];
    const float* b1b    = (const float*)d_in[24];
    const float* cls_W  = (const float*)d_in[25];
    const float* cls_b  = (const float*)d_in[26];
    const float* trans  = (const float*)d_in[27];
    (void)ws_size; (void)in_sizes; (void)n_in; (void)out_size;

    // ---- workspace arena ----
    char* wsb = (char*)d_ws;
    size_t o = 0;
    __hip_bfloat16* Ab     = (__hip_bfloat16*)(wsb + o);   size_t ab_off = o; o += (size_t)M_TOK * DP * 2;
    char*           big    = wsb + o;                      o += (size_t)M_TOK * FF * 2;
    __hip_bfloat16* xb     = (__hip_bfloat16*)(wsb + o);   o += (size_t)M_TOK * DP * 2;
    __hip_bfloat16* Wbff1  = (__hip_bfloat16*)(wsb + o);   o += (size_t)FF * DP * 2;
    __hip_bfloat16* Wbff2  = (__hip_bfloat16*)(wsb + o);   o += (size_t)DP * FF * 2;
    __hip_bfloat16* Wb0    = (__hip_bfloat16*)(wsb + o);   o += (size_t)1024 * DP * 2;
    __hip_bfloat16* Wb1    = (__hip_bfloat16*)(wsb + o);   o += (size_t)1024 * 256 * 2;
    __hip_bfloat16* Whb0f  = (__hip_bfloat16*)(wsb + o);   o += (size_t)G4 * LH * 2;
    __hip_bfloat16* Whb0b  = (__hip_bfloat16*)(wsb + o);   o += (size_t)G4 * LH * 2;
    __hip_bfloat16* Whb1f  = (__hip_bfloat16*)(wsb + o);   o += (size_t)G4 * LH * 2;
    __hip_bfloat16* Whb1b  = (__hip_bfloat16*)(wsb + o);   o += (size_t)G4 * LH * 2;
    __hip_bfloat16* Wbkg1  = (__hip_bfloat16*)(wsb + o);   o += (size_t)H * KGP * 2;
    __hip_bfloat16* Wbcls  = (__hip_bfloat16*)(wsb + o);   o += (size_t)128 * 256 * 2;
    float*          sb0    = (float*)(wsb + o);            o += 1024 * 4;
    float*          sb1    = (float*)(wsb + o);            o += 1024 * 4;
    float*          scores = (float*)(wsb + o);            o += (size_t)M_TOK * 4;
    float*          attw   = (float*)(wsb + o);            o += (size_t)M_TOK * 4;
    float*          emis   = (float*)(wsb + o);            o += (size_t)M_TOK * NT * 4;
    float*          nll    = (float*)(wsb + o);            o += B * 4;
    // big region reuse timeline:
    __hip_bfloat16* h16   = (__hip_bfloat16*)(big + 0);
    __hip_bfloat16* Akg   = (__hip_bfloat16*)(big + 33554432);
    __hip_bfloat16* ff1b  = (__hip_bfloat16*)big;
    float*          pre0f = (float*)(big + 0);
    float*          pre0b = (float*)(big + 16777216);
    __hip_bfloat16* x1b   = (__hip_bfloat16*)(big + 33554432);
    float*          pre1f = (float*)(big + 0);
    float*          pre1b = (float*)(big + 16777216);
    __hip_bfloat16* x2b   = (__hip_bfloat16*)(wsb + ab_off);
    const size_t HALF_STRIDE = 4194304;   // floats: pre0f -> pre0b

    // ---- all weight prep in ONE launch ----
    prep_all_kernel<<<(PREP_TOTAL + 255) / 256, 256, 0, stream>>>(
        ff_W1, ff_W2, Wih0f, Wih0b, Wih1f, Wih1b,
        Whh0f, Whh0b, Whh1f, Whh1b, b0f, b0b, b1f, b1b, cls_W, kg_W1,
        Wbff1, Wbff2, Wb0, Wb1, Whb0f, Whb0b, Whb1f, Whb1b,
        sb0, sb1, Wbcls, Wbkg1);

    // ---- attention front-end ----
    castpad_kg_kernel<<<(M_TOK * KGP + 255) / 256, 256, 0, stream>>>(in_emb, Akg);
    mfma_gemm<<<dim3(H / 128, M_TOK / 128), 256, 0, stream>>>(
        Akg, Wbkg1, kg_b1, nullptr, 0, 0, h16, H, KGP, H, 2);
    ln_score_kernel<<<M_TOK / 4, 256, 0, stream>>>(
        h16, ln_g, ln_b, kg_W2, kg_b2, scores);
    softmax_kernel<<<B, 256, 0, stream>>>(scores, attw);
    combine2_kernel<<<(M_TOK * DP + 255) / 256, 256, 0, stream>>>(in_emb, attw, Ab);

    // ---- FF block ----
    mfma_gemm<<<dim3(FF / 128, M_TOK / 128), 256, 0, stream>>>(
        Ab, Wbff1, ff_b1, nullptr, 0, 0, ff1b, FF, DP, FF, 1 | 2);
    mfma_gemm<<<dim3(DP / 128, M_TOK / 128), 256, 0, stream>>>(
        ff1b, Wbff2, ff_b2, Ab, DP, 0, xb, DP, FF, D, 2 | 16);

    // ---- LSTM layer 0 ----
    mfma_gemm<<<dim3(1024 / 128, M_TOK / 128), 256, 0, stream>>>(
        xb, Wb0, sb0, nullptr, 0, HALF_STRIDE, pre0f, 1024, DP, 1024, 4);
    lstm_mfma_kernel<<<4, 1024, 0, stream>>>(pre0f, pre0b, Whb0f, Whb0b, x1b);

    // ---- LSTM layer 1 ----
    mfma_gemm<<<dim3(1024 / 128, M_TOK / 128), 256, 0, stream>>>(
        x1b, Wb1, sb1, nullptr, 0, HALF_STRIDE, pre1f, 1024, 256, 1024, 4);
    lstm_mfma_kernel<<<4, 1024, 0, stream>>>(pre1f, pre1b, Whb1f, Whb1b, x2b);

    // ---- emissions + CRF + mean ----
    mfma_gemm<<<dim3(1, M_TOK / 128), 256, 0, stream>>>(
        x2b, Wbcls, cls_b, nullptr, 0, 0, emis, 128, 256, NT, 8);
    crf_kernel<<<B, 64, 0, stream>>>(emis, labels, mask, trans, nll);
    mean_kernel<<<1, 64, 0, stream>>>(nll, (float*)d_out);
}

// Round 12
// 990.375 us; speedup vs baseline: 1.2097x; 1.2097x over previous
//
#include <hip/hip_runtime.h>
#include <hip/hip_bf16.h>
#include <math.h>

// Problem dims (fixed by reference)
#define B 32
#define S 256
#define H 768
#define KG 200
#define KGP 224      // KG padded to x32
#define FF 3072
#define LH 128
#define D 968        // H + KG
#define DP 1024      // D padded to multiple of 32
#define NT 11
#define G4 512       // 4*LH
#define START_TAG 9
#define END_TAG 10
#define M_TOK 8192   // B*S
#define L2E 1.4426950408889634f

typedef __attribute__((ext_vector_type(8))) short short8;
typedef __attribute__((ext_vector_type(4))) float f32x4;

// ---------------------------------------------------------------------------
__device__ __forceinline__ void gl_lds16(const void* gptr, void* lptr) {
    __builtin_amdgcn_global_load_lds(
        (const __attribute__((address_space(1))) void*)gptr,
        (__attribute__((address_space(3))) void*)lptr,
        16, 0, 0);
}

// LDS-only barrier (lgkmcnt(0); vmcnt/expcnt unconstrained).
__device__ __forceinline__ void barrier_lds() {
    __builtin_amdgcn_sched_barrier(0);
    __builtin_amdgcn_s_waitcnt(0xC07F);
    __builtin_amdgcn_s_barrier();
    __builtin_amdgcn_sched_barrier(0);
}

__device__ __forceinline__ float frcp(float x) { return __builtin_amdgcn_rcpf(x); }
// RAW hardware v_exp_f32 (exp2). exp2f() w/o -ffast-math lowers to the slow
// __ocml path (round-9 regression); the builtin is the bare instruction.
__device__ __forceinline__ float e2(float x) { return __builtin_amdgcn_exp2f(x); }

__device__ __forceinline__ float fsigmoid(float x) {
    return frcp(1.f + __expf(-x));
}
__device__ __forceinline__ float ftanh(float x) {
    return 1.f - 2.f * frcp(__expf(2.f * x) + 1.f);
}

// ---------------------------------------------------------------------------
// kg slice cast: Akg (M_TOK, KGP) bf16 from in_emb cols H..D, zero pad.
__global__ __launch_bounds__(256) void castpad_kg_kernel(
    const float* __restrict__ in, __hip_bfloat16* __restrict__ Akg)
{
    size_t idx = (size_t)blockIdx.x * 256 + threadIdx.x;
    if (idx >= (size_t)M_TOK * KGP) return;
    int k = (int)(idx % KGP);
    size_t tok = idx / KGP;
    float v = (k < KG) ? in[tok * D + H + k] : 0.f;
    Akg[idx] = __float2bfloat16(v);
}

// ---------------------------------------------------------------------------
// LayerNorm + tanh + W2-dot per token; one wave per token (h in bf16).
__global__ __launch_bounds__(256) void ln_score_kernel(
    const __hip_bfloat16* __restrict__ h16,    // (M_TOK, H)
    const float* __restrict__ ln_g, const float* __restrict__ ln_b,
    const float* __restrict__ W2, const float* __restrict__ b2,
    float* __restrict__ scores)
{
    int wave = threadIdx.x >> 6, lane = threadIdx.x & 63;
    int tok = blockIdx.x * 4 + wave;
    const __hip_bfloat16* hp = h16 + (size_t)tok * H;
    float v[12], s1 = 0.f, s2 = 0.f;
#pragma unroll
    for (int i = 0; i < 12; ++i) {
        v[i] = __bfloat162float(hp[i * 64 + lane]);
        s1 += v[i]; s2 += v[i] * v[i];
    }
#pragma unroll
    for (int o = 32; o > 0; o >>= 1) {
        s1 += __shfl_xor(s1, o, 64);
        s2 += __shfl_xor(s2, o, 64);
    }
    float mu = s1 * (1.f / H);
    float var = s2 * (1.f / H) - mu * mu;
    float rstd = rsqrtf(var + 1e-5f);
    float sc = 0.f;
#pragma unroll
    for (int i = 0; i < 12; ++i) {
        int cidx = i * 64 + lane;
        sc += ftanh((v[i] - mu) * rstd * ln_g[cidx] + ln_b[cidx]) * W2[cidx];
    }
#pragma unroll
    for (int o = 32; o > 0; o >>= 1) sc += __shfl_xor(sc, o, 64);
    if (lane == 0) scores[tok] = sc + b2[0];
}

// ---------------------------------------------------------------------------
__global__ __launch_bounds__(256) void softmax_kernel(
    const float* __restrict__ scores, float* __restrict__ attw)
{
    int b = blockIdx.x, tid = threadIdx.x;
    __shared__ float red[256];
    float v = scores[b * S + tid];
    red[tid] = v; __syncthreads();
    for (int st = 128; st > 0; st >>= 1) {
        if (tid < st) red[tid] = fmaxf(red[tid], red[tid + st]);
        __syncthreads();
    }
    float m = red[0]; __syncthreads();
    float e = expf(v - m);
    red[tid] = e; __syncthreads();
    for (int st = 128; st > 0; st >>= 1) {
        if (tid < st) red[tid] += red[tid + st];
        __syncthreads();
    }
    attw[b * S + tid] = e / red[0];
}

// ---------------------------------------------------------------------------
// combined = [bert, kg*(1+attw)] -> bf16 K-padded (also the FF2 residual).
__global__ __launch_bounds__(256) void combine2_kernel(
    const float* __restrict__ in, const float* __restrict__ attw,
    __hip_bfloat16* __restrict__ Ab)
{
    size_t idx = (size_t)blockIdx.x * 256 + threadIdx.x;
    if (idx >= (size_t)M_TOK * DP) return;
    int d = (int)(idx & (DP - 1));
    size_t tok = idx >> 10;
    float v = 0.f;
    if (d < D) {
        v = in[tok * D + d];
        if (d >= H) v *= (1.f + attw[tok]);
    }
    Ab[idx] = __float2bfloat16(v);
}

// ---------------------------------------------------------------------------
// ONE-SHOT weight prep: all bf16 casts/pads/gate-scales in a single launch.
#define N_FF1  (FF * DP)
#define N_FF2  (DP * FF)
#define N_W0   (512 * DP)
#define N_W1   (512 * 256)
#define N_WHH  65536
#define PREP_TOTAL (N_FF1 + N_FF2 + 2*N_W0 + 2*N_W1 + 4*N_WHH + 2048 + 32768 + H*KGP)
__global__ __launch_bounds__(256) void prep_all_kernel(
    const float* __restrict__ ff_W1, const float* __restrict__ ff_W2,
    const float* __restrict__ Wih0f, const float* __restrict__ Wih0b,
    const float* __restrict__ Wih1f, const float* __restrict__ Wih1b,
    const float* __restrict__ Whh0f, const float* __restrict__ Whh0b,
    const float* __restrict__ Whh1f, const float* __restrict__ Whh1b,
    const float* __restrict__ b0f, const float* __restrict__ b0b,
    const float* __restrict__ b1f, const float* __restrict__ b1b,
    const float* __restrict__ cls_W, const float* __restrict__ kg_W1,
    __hip_bfloat16* __restrict__ Wbff1, __hip_bfloat16* __restrict__ Wbff2,
    __hip_bfloat16* __restrict__ Wb0, __hip_bfloat16* __restrict__ Wb1,
    __hip_bfloat16* __restrict__ Whb0f, __hip_bfloat16* __restrict__ Whb0b,
    __hip_bfloat16* __restrict__ Whb1f, __hip_bfloat16* __restrict__ Whb1b,
    float* __restrict__ sb0, float* __restrict__ sb1,
    __hip_bfloat16* __restrict__ Wbcls, __hip_bfloat16* __restrict__ Wbkg1)
{
    const float SG[4] = { -L2E, -L2E, 2.f * L2E, -L2E };
    size_t idx = (size_t)blockIdx.x * 256 + threadIdx.x;
    if (idx < N_FF1) {
        int n = (int)(idx >> 10), k = (int)(idx & (DP - 1));
        Wbff1[idx] = __float2bfloat16(k < D ? ff_W1[(size_t)n * D + k] : 0.f);
        return;
    }
    idx -= N_FF1;
    if (idx < N_FF2) {
        int n = (int)(idx / FF), k = (int)(idx % FF);
        Wbff2[idx] = __float2bfloat16(n < D ? ff_W2[(size_t)n * FF + k] : 0.f);
        return;
    }
    idx -= N_FF2;
    if (idx < 2 * N_W0) {
        int half = (int)(idx / N_W0); size_t i = idx % N_W0;
        int n = (int)(i >> 10), k = (int)(i & (DP - 1));
        const float* src = half ? Wih0b : Wih0f;
        float v = (k < D) ? src[(size_t)n * D + k] * SG[(n >> 7) & 3] : 0.f;
        Wb0[idx] = __float2bfloat16(v);
        return;
    }
    idx -= 2 * N_W0;
    if (idx < 2 * N_W1) {
        int half = (int)(idx / N_W1); size_t i = idx % N_W1;
        int n = (int)(i >> 8);
        const float* src = half ? Wih1b : Wih1f;
        float v = src[i] * SG[(n >> 7) & 3];
        Wb1[idx] = __float2bfloat16(v);
        return;
    }
    idx -= 2 * N_W1;
    if (idx < 4 * N_WHH) {
        int seg = (int)(idx >> 16), i = (int)(idx & (N_WHH - 1));
        float s = SG[i >> 14];
        const float* srcs[4] = { Whh0f, Whh0b, Whh1f, Whh1b };
        __hip_bfloat16* dsts[4] = { Whb0f, Whb0b, Whb1f, Whb1b };
        dsts[seg][i] = __float2bfloat16(srcs[seg][i] * s);
        return;
    }
    idx -= 4 * N_WHH;
    if (idx < 1024) {
        int n = (int)idx;
        sb0[n] = ((n < 512) ? b0f[n] : b0b[n - 512]) * SG[(n >> 7) & 3];
        return;
    }
    idx -= 1024;
    if (idx < 1024) {
        int n = (int)idx;
        sb1[n] = ((n < 512) ? b1f[n] : b1b[n - 512]) * SG[(n >> 7) & 3];
        return;
    }
    idx -= 1024;
    if (idx < 32768) {
        int n = (int)(idx >> 8), k = (int)(idx & 255);
        Wbcls[idx] = __float2bfloat16(n < NT ? cls_W[n * 256 + k] : 0.f);
        return;
    }
    idx -= 32768;
    if (idx < (size_t)H * KGP) {
        int n = (int)(idx / KGP), k = (int)(idx % KGP);
        Wbkg1[idx] = __float2bfloat16(k < KG ? kg_W1[(size_t)n * KG + k] : 0.f);
    }
}

// ---------------------------------------------------------------------------
// bf16 MFMA GEMM: C(M,Np) = act(A(M,Kp) @ W(Np,Kp)^T + bias) [+ res].
// flags: bit0 relu; bit1 bf16 out; bit2 LSTM gate-interleave fp32 store;
// bit3 compact fp32 store stride N_real; bit4 res is bf16.
__global__ __launch_bounds__(256) void mfma_gemm(
    const __hip_bfloat16* __restrict__ A,
    const __hip_bfloat16* __restrict__ Wb,
    const float* __restrict__ bias,
    const void* __restrict__ res, int res_ld, size_t half_stride,
    void* __restrict__ Cout,
    int Np, int Kp, int N_real, int flags)
{
    __shared__ short As[128 * 32];
    __shared__ short Bs[128 * 32];
    const int tid  = threadIdx.x;
    const int wave = tid >> 6;
    const int lane = tid & 63;
    const int bm = blockIdx.y * 128, bn = blockIdx.x * 128;
    const int sr = lane >> 2;
    const int sc = (lane & 3) * 8;
    const int fr = lane & 15;
    const int fq = lane >> 4;
    const int wm = (wave >> 1) * 64, wn = (wave & 1) * 64;

    f32x4 acc[4][4];
#pragma unroll
    for (int i = 0; i < 4; ++i)
#pragma unroll
        for (int j = 0; j < 4; ++j) acc[i][j] = (f32x4){0.f, 0.f, 0.f, 0.f};

    const __hip_bfloat16* ga0 = A  + (size_t)(bm + wave * 32      + sr) * Kp + sc;
    const __hip_bfloat16* ga1 = A  + (size_t)(bm + wave * 32 + 16 + sr) * Kp + sc;
    const __hip_bfloat16* gb0 = Wb + (size_t)(bn + wave * 32      + sr) * Kp + sc;
    const __hip_bfloat16* gb1 = Wb + (size_t)(bn + wave * 32 + 16 + sr) * Kp + sc;
    short* lA0 = &As[(wave * 2 + 0) * 512];
    short* lA1 = &As[(wave * 2 + 1) * 512];
    short* lB0 = &Bs[(wave * 2 + 0) * 512];
    short* lB1 = &Bs[(wave * 2 + 1) * 512];

    for (int k0 = 0; k0 < Kp; k0 += 32) {
        gl_lds16(ga0 + k0, lA0);
        gl_lds16(ga1 + k0, lA1);
        gl_lds16(gb0 + k0, lB0);
        gl_lds16(gb1 + k0, lB1);
        __syncthreads();

        short8 af[4], bfr[4];
#pragma unroll
        for (int mi = 0; mi < 4; ++mi)
            af[mi] = *(const short8*)&As[(wm + mi * 16 + fr) * 32 + fq * 8];
#pragma unroll
        for (int ni = 0; ni < 4; ++ni)
            bfr[ni] = *(const short8*)&Bs[(wn + ni * 16 + fr) * 32 + fq * 8];
#pragma unroll
        for (int mi = 0; mi < 4; ++mi)
#pragma unroll
            for (int ni = 0; ni < 4; ++ni)
                acc[mi][ni] = __builtin_amdgcn_mfma_f32_16x16x32_bf16(
                    af[mi], bfr[ni], acc[mi][ni], 0, 0, 0);
        __syncthreads();
    }

    const bool relu = flags & 1;
    const bool obf  = flags & 2;
    const bool gate = flags & 4;
    const bool cmp  = flags & 8;
    const bool rbf  = flags & 16;
#pragma unroll
    for (int mi = 0; mi < 4; ++mi) {
#pragma unroll
        for (int ni = 0; ni < 4; ++ni) {
#pragma unroll
            for (int r = 0; r < 4; ++r) {
                int m = bm + wm + mi * 16 + fq * 4 + r;
                int n = bn + wn + ni * 16 + fr;
                float v = acc[mi][ni][r];
                if (n < N_real) {
                    v += bias[n];
                    if (relu) v = fmaxf(v, 0.f);
                    if (res) {
                        if (rbf)
                            v += __bfloat162float(
                                ((const __hip_bfloat16*)res)[(size_t)m * res_ld + n]);
                        else
                            v += ((const float*)res)[(size_t)m * res_ld + n];
                    }
                } else {
                    v = 0.f;
                }
                if (gate) {
                    ((float*)Cout)[(size_t)m * 512 + ((n & 127) << 2)
                                   + ((n >> 7) & 3) + (size_t)(n >> 9) * half_stride] = v;
                } else if (cmp) {
                    if (n < N_real)
                        ((float*)Cout)[(size_t)m * N_real + n] = v;
                } else if (obf) {
                    ((__hip_bfloat16*)Cout)[(size_t)m * Np + n] = __float2bfloat16(v);
                } else {
                    ((float*)Cout)[(size_t)m * Np + n] = v;
                }
            }
        }
    }
}

// ---------------------------------------------------------------------------
// Batched MFMA LSTM recurrence, 8 blocks x 1024 threads, 1 h per lane.
// Block = (dir, sample-octet). The 8 samples sit at EVEN LDS rows 2j, so
// each lane's quad holds exactly 2 valid acc regs (0 and 2); the 2 wave-
// groups split those -> 1 h/lane, all lanes active, trans issue per wave
// halves vs the 16-sample version. Odd rows stay zero (init once).
__global__ __launch_bounds__(1024, 4) void lstm_mfma_kernel(
    const float* __restrict__ pre_f, const float* __restrict__ pre_b,
    const __hip_bfloat16* __restrict__ whh_f,
    const __hip_bfloat16* __restrict__ whh_b,
    __hip_bfloat16* __restrict__ out)   // (B,S,2*LH) bf16
{
    const int dir = blockIdx.x >> 2;
    const int s0  = (blockIdx.x & 3) * 8;
    const float* pre = dir ? pre_b : pre_f;
    const __hip_bfloat16* whh = dir ? whh_b : whh_f;

    const int tid  = threadIdx.x;
    const int w16  = tid >> 6;
    const int grp  = __builtin_amdgcn_readfirstlane(w16 >> 3);  // 0/1, uniform
    const int w8   = w16 & 7;
    const int lane = tid & 63;
    const int l15  = lane & 15;
    const int q    = lane >> 4;
    const int col  = 16 * w8 + l15;
    const int samp = 2 * q + grp;       // 0..7 within octet
    const int lrow = 4 * q + 2 * grp;   // LDS row = 2*samp (even)

    short8 bf[4][4];
#pragma unroll
    for (int t = 0; t < 4; ++t) {
        const __hip_bfloat16* wrow = whh + (size_t)(t * 128 + col) * LH;
#pragma unroll
        for (int kt = 0; kt < 4; ++kt)
            bf[t][kt] = *(const short8*)(wrow + kt * 32 + q * 8);
    }

    __shared__ __hip_bfloat16 h_lds[2][16][136];
    for (int i = tid; i < 2 * 16 * 136; i += 1024)
        ((__hip_bfloat16*)h_lds)[i] = __float2bfloat16(0.f);

    float c0 = 0.f;

    const int t0 = dir ? (S - 1) : 0;
    const int stepoff = dir ? -G4 : G4;
    const int outoff  = dir ? -256 : 256;
    const int row0 = s0 + samp;         // global sample row 0..31

    const float* pp0 = pre + ((size_t)row0 * S + t0) * G4 + col * 4;
    __hip_bfloat16* op0 = out + ((size_t)row0 * S + t0) * 256 + dir * 128 + col;

    float4 pcA = *(const float4*)pp0; pp0 += stepoff;

    auto body = [&](const __hip_bfloat16 (&rb)[16][136],
                    __hip_bfloat16 (&wb)[16][136],
                    const float4& g0) {
        short8 af[4];
#pragma unroll
        for (int kt = 0; kt < 4; ++kt)
            af[kt] = *(const short8*)&rb[l15][kt * 32 + q * 8];

        f32x4 acc[4];
#pragma unroll
        for (int t = 0; t < 4; ++t) {
            acc[t] = (f32x4){0.f, 0.f, 0.f, 0.f};
#pragma unroll
            for (int kt = 0; kt < 4; ++kt)
                acc[t] = __builtin_amdgcn_mfma_f32_16x16x32_bf16(
                    af[kt], bf[t][kt], acc[t], 0, 0, 0);
        }

        float a0[4];
        if (grp == 0) {                 // uniform branch: reg 0 vs reg 2
#pragma unroll
            for (int t = 0; t < 4; ++t) a0[t] = acc[t][0];
        } else {
#pragma unroll
            for (int t = 0; t < 4; ++t) a0[t] = acc[t][2];
        }

        float Ei = e2(a0[0] + g0.x);
        float Ef = e2(a0[1] + g0.y);
        float Eg = e2(fminf(a0[2] + g0.z, 80.f));
        float Eo = e2(a0[3] + g0.w);
        float T  = (Eg - 1.f) * frcp((1.f + Ei) * (Eg + 1.f));
        c0 = fmaf(c0, frcp(1.f + Ef), T);
        float E2 = e2(fminf(c0 * (2.f * L2E), 80.f));
        float h0 = (E2 - 1.f) * frcp((1.f + Eo) * (E2 + 1.f));

        __hip_bfloat16 hb0 = __float2bfloat16(h0);
        wb[lrow][col] = hb0;
        *op0 = hb0; op0 += outoff;
    };

    barrier_lds();

    for (int it = 0; it < S / 2; ++it) {
        float4 pcB = *(const float4*)pp0; pp0 += stepoff;
        body(h_lds[0], h_lds[1], pcA);
        barrier_lds();
        pcA = *(const float4*)pp0; pp0 += stepoff;
        body(h_lds[1], h_lds[0], pcB);
        barrier_lds();
    }
}

// ---------------------------------------------------------------------------
// CRF NLL per sample (round-10 version: __syncthreads + em/mask prefetch)
__global__ __launch_bounds__(64) void crf_kernel(
    const float* __restrict__ em, const int* __restrict__ labels,
    const int* __restrict__ mask, const float* __restrict__ trans,
    float* __restrict__ nll)
{
    int b = blockIdx.x, tid = threadIdx.x;
    __shared__ float tr[NT * NT];
    __shared__ float alpha[NT];
    __shared__ float red[64];
    __shared__ float gold_s;

    for (int i = tid; i < NT * NT; i += 64) tr[i] = trans[i];
    __syncthreads();

    float emit = 0.f, pair = 0.f, lenf = 0.f;
    for (int s = tid; s < S; s += 64) {
        int lab = labels[b * S + s];
        float mf = (float)mask[b * S + s];
        emit += em[(size_t)(b * S + s) * NT + lab] * mf;
        lenf += mf;
        if (s >= 1) {
            int lp = labels[b * S + s - 1];
            pair += tr[lp * NT + lab] * mf;
        }
    }
    red[tid] = emit; __syncthreads();
    for (int st = 32; st > 0; st >>= 1) { if (tid < st) red[tid] += red[tid + st]; __syncthreads(); }
    float emit_tot = red[0]; __syncthreads();
    red[tid] = pair; __syncthreads();
    for (int st = 32; st > 0; st >>= 1) { if (tid < st) red[tid] += red[tid + st]; __syncthreads(); }
    float pair_tot = red[0]; __syncthreads();
    red[tid] = lenf; __syncthreads();
    for (int st = 32; st > 0; st >>= 1) { if (tid < st) red[tid] += red[tid + st]; __syncthreads(); }
    float len_tot = red[0]; __syncthreads();

    if (tid == 0) {
        int len_i = (int)(len_tot + 0.5f);
        int last = labels[b * S + len_i - 1];
        gold_s = tr[START_TAG * NT + labels[b * S]] + emit_tot + pair_tot
               + tr[last * NT + END_TAG];
    }
    if (tid < NT) alpha[tid] = tr[START_TAG * NT + tid] + em[(size_t)(b * S) * NT + tid];
    __syncthreads();

    float ecur = (tid < NT) ? em[(size_t)(b * S + 1) * NT + tid] : 0.f;
    int   mcur = mask[b * S + 1];

    for (int t = 1; t < S; ++t) {
        float enxt = 0.f; int mnxt = 0;
        if (t + 1 < S) {
            if (tid < NT) enxt = em[(size_t)(b * S + t + 1) * NT + tid];
            mnxt = mask[b * S + t + 1];
        }
        float newv = 0.f;
        if (tid < NT) {
            float vals[NT];
            float m = -1e30f;
#pragma unroll
            for (int i2 = 0; i2 < NT; ++i2) {
                float v = alpha[i2] + tr[i2 * NT + tid];
                vals[i2] = v;
                m = fmaxf(m, v);
            }
            float ssum = 0.f;
#pragma unroll
            for (int i2 = 0; i2 < NT; ++i2) ssum += __expf(vals[i2] - m);
            newv = m + __logf(ssum) + ecur;
            if (!(mcur > 0)) newv = alpha[tid];
        }
        __syncthreads();
        if (tid < NT) alpha[tid] = newv;
        __syncthreads();
        ecur = enxt; mcur = mnxt;
    }

    if (tid < NT) red[tid] = alpha[tid] + tr[tid * NT + END_TAG];
    __syncthreads();
    if (tid == 0) {
        float m = -1e30f;
        for (int j = 0; j < NT; ++j) m = fmaxf(m, red[j]);
        float ssum = 0.f;
        for (int j = 0; j < NT; ++j) ssum += __expf(red[j] - m);
        float logZ = m + __logf(ssum);
        nll[b] = logZ - gold_s;
    }
}

__global__ void mean_kernel(const float* __restrict__ nll, float* __restrict__ out)
{
    if (threadIdx.x == 0) {
        float s = 0.f;
        for (int i = 0; i < B; ++i) s += nll[i];
        out[0] = s / (float)B;
    }
}

// ---------------------------------------------------------------------------
extern "C" void kernel_launch(void* const* d_in, const int* in_sizes, int n_in,
                              void* d_out, int out_size, void* d_ws, size_t ws_size,
                              hipStream_t stream)
{
    const float* in_emb = (const float*)d_in[0];
    const int*   mask   = (const int*)d_in[1];
    const int*   labels = (const int*)d_in[2];
    const float* kg_W1  = (const float*)d_in[3];
    const float* kg_b1  = (const float*)d_in[4];
    const float* ln_g   = (const float*)d_in[5];
    const float* ln_b   = (const float*)d_in[6];
    const float* kg_W2  = (const float*)d_in[7];
    const float* kg_b2  = (const float*)d_in[8];
    const float* ff_W1  = (const float*)d_in[9];
    const float* ff_b1  = (const float*)d_in[10];
    const float* ff_W2  = (const float*)d_in[11];
    const float* ff_b2  = (const float*)d_in[12];
    const float* Wih0f  = (const float*)d_in[13];
    const float* Whh0f  = (const float*)d_in[14];
    const float* b0f    = (const float*)d_in[15];
    const float* Wih0b  = (const float*)d_in[16];
    const float* Whh0b  = (const float*)d_in[17];
    const float* b0b    = (const float*)d_in[18];
    const float* Wih1f  = (const float*)d_in[19];
    const float* Whh1f  = (const float*)d_in[20];
    const float* b1f    = (const float*)d_in[21];
    const float* Wih1b  = (const float*)d_in[22];
    const float* Whh1b  = (const float*)d_in[23];
    const float* b1b    = (const float*)d_in[24];
    const float* cls_W  = (const float*)d_in[25];
    const float* cls_b  = (const float*)d_in[26];
    const float* trans  = (const float*)d_in[27];
    (void)ws_size; (void)in_sizes; (void)n_in; (void)out_size;

    // ---- workspace arena ----
    char* wsb = (char*)d_ws;
    size_t o = 0;
    __hip_bfloat16* Ab     = (__hip_bfloat16*)(wsb + o);   size_t ab_off = o; o += (size_t)M_TOK * DP * 2;
    char*           big    = wsb + o;                      o += (size_t)M_TOK * FF * 2;
    __hip_bfloat16* xb     = (__hip_bfloat16*)(wsb + o);   o += (size_t)M_TOK * DP * 2;
    __hip_bfloat16* Wbff1  = (__hip_bfloat16*)(wsb + o);   o += (size_t)FF * DP * 2;
    __hip_bfloat16* Wbff2  = (__hip_bfloat16*)(wsb + o);   o += (size_t)DP * FF * 2;
    __hip_bfloat16* Wb0    = (__hip_bfloat16*)(wsb + o);   o += (size_t)1024 * DP * 2;
    __hip_bfloat16* Wb1    = (__hip_bfloat16*)(wsb + o);   o += (size_t)1024 * 256 * 2;
    __hip_bfloat16* Whb0f  = (__hip_bfloat16*)(wsb + o);   o += (size_t)G4 * LH * 2;
    __hip_bfloat16* Whb0b  = (__hip_bfloat16*)(wsb + o);   o += (size_t)G4 * LH * 2;
    __hip_bfloat16* Whb1f  = (__hip_bfloat16*)(wsb + o);   o += (size_t)G4 * LH * 2;
    __hip_bfloat16* Whb1b  = (__hip_bfloat16*)(wsb + o);   o += (size_t)G4 * LH * 2;
    __hip_bfloat16* Wbkg1  = (__hip_bfloat16*)(wsb + o);   o += (size_t)H * KGP * 2;
    __hip_bfloat16* Wbcls  = (__hip_bfloat16*)(wsb + o);   o += (size_t)128 * 256 * 2;
    float*          sb0    = (float*)(wsb + o);            o += 1024 * 4;
    float*          sb1    = (float*)(wsb + o);            o += 1024 * 4;
    float*          scores = (float*)(wsb + o);            o += (size_t)M_TOK * 4;
    float*          attw   = (float*)(wsb + o);            o += (size_t)M_TOK * 4;
    float*          emis   = (float*)(wsb + o);            o += (size_t)M_TOK * NT * 4;
    float*          nll    = (float*)(wsb + o);            o += B * 4;
    // big region reuse timeline:
    __hip_bfloat16* h16   = (__hip_bfloat16*)(big + 0);
    __hip_bfloat16* Akg   = (__hip_bfloat16*)(big + 33554432);
    __hip_bfloat16* ff1b  = (__hip_bfloat16*)big;
    float*          pre0f = (float*)(big + 0);
    float*          pre0b = (float*)(big + 16777216);
    __hip_bfloat16* x1b   = (__hip_bfloat16*)(big + 33554432);
    float*          pre1f = (float*)(big + 0);
    float*          pre1b = (float*)(big + 16777216);
    __hip_bfloat16* x2b   = (__hip_bfloat16*)(wsb + ab_off);
    const size_t HALF_STRIDE = 4194304;   // floats: pre0f -> pre0b

    // ---- all weight prep in ONE launch ----
    prep_all_kernel<<<(PREP_TOTAL + 255) / 256, 256, 0, stream>>>(
        ff_W1, ff_W2, Wih0f, Wih0b, Wih1f, Wih1b,
        Whh0f, Whh0b, Whh1f, Whh1b, b0f, b0b, b1f, b1b, cls_W, kg_W1,
        Wbff1, Wbff2, Wb0, Wb1, Whb0f, Whb0b, Whb1f, Whb1b,
        sb0, sb1, Wbcls, Wbkg1);

    // ---- attention front-end ----
    castpad_kg_kernel<<<(M_TOK * KGP + 255) / 256, 256, 0, stream>>>(in_emb, Akg);
    mfma_gemm<<<dim3(H / 128, M_TOK / 128), 256, 0, stream>>>(
        Akg, Wbkg1, kg_b1, nullptr, 0, 0, h16, H, KGP, H, 2);
    ln_score_kernel<<<M_TOK / 4, 256, 0, stream>>>(
        h16, ln_g, ln_b, kg_W2, kg_b2, scores);
    softmax_kernel<<<B, 256, 0, stream>>>(scores, attw);
    combine2_kernel<<<(M_TOK * DP + 255) / 256, 256, 0, stream>>>(in_emb, attw, Ab);

    // ---- FF block ----
    mfma_gemm<<<dim3(FF / 128, M_TOK / 128), 256, 0, stream>>>(
        Ab, Wbff1, ff_b1, nullptr, 0, 0, ff1b, FF, DP, FF, 1 | 2);
    mfma_gemm<<<dim3(DP / 128, M_TOK / 128), 256, 0, stream>>>(
        ff1b, Wbff2, ff_b2, Ab, DP, 0, xb, DP, FF, D, 2 | 16);

    // ---- LSTM layer 0 ----
    mfma_gemm<<<dim3(1024 / 128, M_TOK / 128), 256, 0, stream>>>(
        xb, Wb0, sb0, nullptr, 0, HALF_STRIDE, pre0f, 1024, DP, 1024, 4);
    lstm_mfma_kernel<<<8, 1024, 0, stream>>>(pre0f, pre0b, Whb0f, Whb0b, x1b);

    // ---- LSTM layer 1 ----
    mfma_gemm<<<dim3(1024 / 128, M_TOK / 128), 256, 0, stream>>>(
        x1b, Wb1, sb1, nullptr, 0, HALF_STRIDE, pre1f, 1024, 256, 1024, 4);
    lstm_mfma_kernel<<<8, 1024, 0, stream>>>(pre1f, pre1b, Whb1f, Whb1b, x2b);

    // ---- emissions + CRF + mean ----
    mfma_gemm<<<dim3(1, M_TOK / 128), 256, 0, stream>>>(
        x2b, Wbcls, cls_b, nullptr, 0, 0, emis, 128, 256, NT, 8);
    crf_kernel<<<B, 64, 0, stream>>>(emis, labels, mask, trans, nll);
    mean_kernel<<<1, 64, 0, stream>>>(nll, (float*)d_out);
}

// Round 13
// 824.295 us; speedup vs baseline: 1.4535x; 1.2015x over previous
//
#include <hip/hip_runtime.h>
#include <hip/hip_bf16.h>
#include <math.h>

// Problem dims (fixed by reference)
#define B 32
#define S 256
#define H 768
#define KG 200
#define KGP 224      // KG padded to x32
#define FF 3072
#define LH 128
#define D 968        // H + KG
#define DP 1024      // D padded to multiple of 32
#define NT 11
#define G4 512       // 4*LH
#define START_TAG 9
#define END_TAG 10
#define M_TOK 8192   // B*S
#define L2E 1.4426950408889634f

typedef __attribute__((ext_vector_type(8))) short short8;
typedef __attribute__((ext_vector_type(4))) float f32x4;

// ---------------------------------------------------------------------------
__device__ __forceinline__ void gl_lds16(const void* gptr, void* lptr) {
    __builtin_amdgcn_global_load_lds(
        (const __attribute__((address_space(1))) void*)gptr,
        (__attribute__((address_space(3))) void*)lptr,
        16, 0, 0);
}

// LDS-only barrier (lgkmcnt(0); vmcnt/expcnt unconstrained).
__device__ __forceinline__ void barrier_lds() {
    __builtin_amdgcn_sched_barrier(0);
    __builtin_amdgcn_s_waitcnt(0xC07F);
    __builtin_amdgcn_s_barrier();
    __builtin_amdgcn_sched_barrier(0);
}

__device__ __forceinline__ float frcp(float x) { return __builtin_amdgcn_rcpf(x); }
// RAW hardware v_exp_f32 (exp2). exp2f() w/o -ffast-math lowers to the slow
// __ocml path (round-9 regression); the builtin is the bare instruction.
__device__ __forceinline__ float e2(float x) { return __builtin_amdgcn_exp2f(x); }

__device__ __forceinline__ float fsigmoid(float x) {
    return frcp(1.f + __expf(-x));
}
__device__ __forceinline__ float ftanh(float x) {
    return 1.f - 2.f * frcp(__expf(2.f * x) + 1.f);
}

// ---------------------------------------------------------------------------
// kg slice cast: Akg (M_TOK, KGP) bf16 from in_emb cols H..D, zero pad.
__global__ __launch_bounds__(256) void castpad_kg_kernel(
    const float* __restrict__ in, __hip_bfloat16* __restrict__ Akg)
{
    size_t idx = (size_t)blockIdx.x * 256 + threadIdx.x;
    if (idx >= (size_t)M_TOK * KGP) return;
    int k = (int)(idx % KGP);
    size_t tok = idx / KGP;
    float v = (k < KG) ? in[tok * D + H + k] : 0.f;
    Akg[idx] = __float2bfloat16(v);
}

// ---------------------------------------------------------------------------
// LayerNorm + tanh + W2-dot per token; one wave per token (h in bf16).
__global__ __launch_bounds__(256) void ln_score_kernel(
    const __hip_bfloat16* __restrict__ h16,    // (M_TOK, H)
    const float* __restrict__ ln_g, const float* __restrict__ ln_b,
    const float* __restrict__ W2, const float* __restrict__ b2,
    float* __restrict__ scores)
{
    int wave = threadIdx.x >> 6, lane = threadIdx.x & 63;
    int tok = blockIdx.x * 4 + wave;
    const __hip_bfloat16* hp = h16 + (size_t)tok * H;
    float v[12], s1 = 0.f, s2 = 0.f;
#pragma unroll
    for (int i = 0; i < 12; ++i) {
        v[i] = __bfloat162float(hp[i * 64 + lane]);
        s1 += v[i]; s2 += v[i] * v[i];
    }
#pragma unroll
    for (int o = 32; o > 0; o >>= 1) {
        s1 += __shfl_xor(s1, o, 64);
        s2 += __shfl_xor(s2, o, 64);
    }
    float mu = s1 * (1.f / H);
    float var = s2 * (1.f / H) - mu * mu;
    float rstd = rsqrtf(var + 1e-5f);
    float sc = 0.f;
#pragma unroll
    for (int i = 0; i < 12; ++i) {
        int cidx = i * 64 + lane;
        sc += ftanh((v[i] - mu) * rstd * ln_g[cidx] + ln_b[cidx]) * W2[cidx];
    }
#pragma unroll
    for (int o = 32; o > 0; o >>= 1) sc += __shfl_xor(sc, o, 64);
    if (lane == 0) scores[tok] = sc + b2[0];
}

// ---------------------------------------------------------------------------
__global__ __launch_bounds__(256) void softmax_kernel(
    const float* __restrict__ scores, float* __restrict__ attw)
{
    int b = blockIdx.x, tid = threadIdx.x;
    __shared__ float red[256];
    float v = scores[b * S + tid];
    red[tid] = v; __syncthreads();
    for (int st = 128; st > 0; st >>= 1) {
        if (tid < st) red[tid] = fmaxf(red[tid], red[tid + st]);
        __syncthreads();
    }
    float m = red[0]; __syncthreads();
    float e = expf(v - m);
    red[tid] = e; __syncthreads();
    for (int st = 128; st > 0; st >>= 1) {
        if (tid < st) red[tid] += red[tid + st];
        __syncthreads();
    }
    attw[b * S + tid] = e / red[0];
}

// ---------------------------------------------------------------------------
// combined = [bert, kg*(1+attw)] -> bf16 K-padded (also the FF2 residual).
__global__ __launch_bounds__(256) void combine2_kernel(
    const float* __restrict__ in, const float* __restrict__ attw,
    __hip_bfloat16* __restrict__ Ab)
{
    size_t idx = (size_t)blockIdx.x * 256 + threadIdx.x;
    if (idx >= (size_t)M_TOK * DP) return;
    int d = (int)(idx & (DP - 1));
    size_t tok = idx >> 10;
    float v = 0.f;
    if (d < D) {
        v = in[tok * D + d];
        if (d >= H) v *= (1.f + attw[tok]);
    }
    Ab[idx] = __float2bfloat16(v);
}

// ---------------------------------------------------------------------------
// ONE-SHOT weight prep: all bf16 casts/pads/gate-scales in a single launch.
#define N_FF1  (FF * DP)
#define N_FF2  (DP * FF)
#define N_W0   (512 * DP)
#define N_W1   (512 * 256)
#define N_WHH  65536
#define PREP_TOTAL (N_FF1 + N_FF2 + 2*N_W0 + 2*N_W1 + 4*N_WHH + 2048 + 32768 + H*KGP)
__global__ __launch_bounds__(256) void prep_all_kernel(
    const float* __restrict__ ff_W1, const float* __restrict__ ff_W2,
    const float* __restrict__ Wih0f, const float* __restrict__ Wih0b,
    const float* __restrict__ Wih1f, const float* __restrict__ Wih1b,
    const float* __restrict__ Whh0f, const float* __restrict__ Whh0b,
    const float* __restrict__ Whh1f, const float* __restrict__ Whh1b,
    const float* __restrict__ b0f, const float* __restrict__ b0b,
    const float* __restrict__ b1f, const float* __restrict__ b1b,
    const float* __restrict__ cls_W, const float* __restrict__ kg_W1,
    __hip_bfloat16* __restrict__ Wbff1, __hip_bfloat16* __restrict__ Wbff2,
    __hip_bfloat16* __restrict__ Wb0, __hip_bfloat16* __restrict__ Wb1,
    __hip_bfloat16* __restrict__ Whb0f, __hip_bfloat16* __restrict__ Whb0b,
    __hip_bfloat16* __restrict__ Whb1f, __hip_bfloat16* __restrict__ Whb1b,
    float* __restrict__ sb0, float* __restrict__ sb1,
    __hip_bfloat16* __restrict__ Wbcls, __hip_bfloat16* __restrict__ Wbkg1)
{
    const float SG[4] = { -L2E, -L2E, 2.f * L2E, -L2E };
    size_t idx = (size_t)blockIdx.x * 256 + threadIdx.x;
    if (idx < N_FF1) {
        int n = (int)(idx >> 10), k = (int)(idx & (DP - 1));
        Wbff1[idx] = __float2bfloat16(k < D ? ff_W1[(size_t)n * D + k] : 0.f);
        return;
    }
    idx -= N_FF1;
    if (idx < N_FF2) {
        int n = (int)(idx / FF), k = (int)(idx % FF);
        Wbff2[idx] = __float2bfloat16(n < D ? ff_W2[(size_t)n * FF + k] : 0.f);
        return;
    }
    idx -= N_FF2;
    if (idx < 2 * N_W0) {
        int half = (int)(idx / N_W0); size_t i = idx % N_W0;
        int n = (int)(i >> 10), k = (int)(i & (DP - 1));
        const float* src = half ? Wih0b : Wih0f;
        float v = (k < D) ? src[(size_t)n * D + k] * SG[(n >> 7) & 3] : 0.f;
        Wb0[idx] = __float2bfloat16(v);
        return;
    }
    idx -= 2 * N_W0;
    if (idx < 2 * N_W1) {
        int half = (int)(idx / N_W1); size_t i = idx % N_W1;
        int n = (int)(i >> 8);
        const float* src = half ? Wih1b : Wih1f;
        float v = src[i] * SG[(n >> 7) & 3];
        Wb1[idx] = __float2bfloat16(v);
        return;
    }
    idx -= 2 * N_W1;
    if (idx < 4 * N_WHH) {
        int seg = (int)(idx >> 16), i = (int)(idx & (N_WHH - 1));
        float s = SG[i >> 14];
        const float* srcs[4] = { Whh0f, Whh0b, Whh1f, Whh1b };
        __hip_bfloat16* dsts[4] = { Whb0f, Whb0b, Whb1f, Whb1b };
        dsts[seg][i] = __float2bfloat16(srcs[seg][i] * s);
        return;
    }
    idx -= 4 * N_WHH;
    if (idx < 1024) {
        int n = (int)idx;
        sb0[n] = ((n < 512) ? b0f[n] : b0b[n - 512]) * SG[(n >> 7) & 3];
        return;
    }
    idx -= 1024;
    if (idx < 1024) {
        int n = (int)idx;
        sb1[n] = ((n < 512) ? b1f[n] : b1b[n - 512]) * SG[(n >> 7) & 3];
        return;
    }
    idx -= 1024;
    if (idx < 32768) {
        int n = (int)(idx >> 8), k = (int)(idx & 255);
        Wbcls[idx] = __float2bfloat16(n < NT ? cls_W[n * 256 + k] : 0.f);
        return;
    }
    idx -= 32768;
    if (idx < (size_t)H * KGP) {
        int n = (int)(idx / KGP), k = (int)(idx % KGP);
        Wbkg1[idx] = __float2bfloat16(k < KG ? kg_W1[(size_t)n * KG + k] : 0.f);
    }
}

// ---------------------------------------------------------------------------
// bf16 MFMA GEMM: C(M,Np) = act(A(M,Kp) @ W(Np,Kp)^T + bias) [+ res].
// flags: bit0 relu; bit1 bf16 out; bit2 LSTM gate-interleave fp32 store;
// bit3 compact fp32 store stride N_real; bit4 res is bf16.
__global__ __launch_bounds__(256) void mfma_gemm(
    const __hip_bfloat16* __restrict__ A,
    const __hip_bfloat16* __restrict__ Wb,
    const float* __restrict__ bias,
    const void* __restrict__ res, int res_ld, size_t half_stride,
    void* __restrict__ Cout,
    int Np, int Kp, int N_real, int flags)
{
    __shared__ short As[128 * 32];
    __shared__ short Bs[128 * 32];
    const int tid  = threadIdx.x;
    const int wave = tid >> 6;
    const int lane = tid & 63;
    const int bm = blockIdx.y * 128, bn = blockIdx.x * 128;
    const int sr = lane >> 2;
    const int sc = (lane & 3) * 8;
    const int fr = lane & 15;
    const int fq = lane >> 4;
    const int wm = (wave >> 1) * 64, wn = (wave & 1) * 64;

    f32x4 acc[4][4];
#pragma unroll
    for (int i = 0; i < 4; ++i)
#pragma unroll
        for (int j = 0; j < 4; ++j) acc[i][j] = (f32x4){0.f, 0.f, 0.f, 0.f};

    const __hip_bfloat16* ga0 = A  + (size_t)(bm + wave * 32      + sr) * Kp + sc;
    const __hip_bfloat16* ga1 = A  + (size_t)(bm + wave * 32 + 16 + sr) * Kp + sc;
    const __hip_bfloat16* gb0 = Wb + (size_t)(bn + wave * 32      + sr) * Kp + sc;
    const __hip_bfloat16* gb1 = Wb + (size_t)(bn + wave * 32 + 16 + sr) * Kp + sc;
    short* lA0 = &As[(wave * 2 + 0) * 512];
    short* lA1 = &As[(wave * 2 + 1) * 512];
    short* lB0 = &Bs[(wave * 2 + 0) * 512];
    short* lB1 = &Bs[(wave * 2 + 1) * 512];

    for (int k0 = 0; k0 < Kp; k0 += 32) {
        gl_lds16(ga0 + k0, lA0);
        gl_lds16(ga1 + k0, lA1);
        gl_lds16(gb0 + k0, lB0);
        gl_lds16(gb1 + k0, lB1);
        __syncthreads();

        short8 af[4], bfr[4];
#pragma unroll
        for (int mi = 0; mi < 4; ++mi)
            af[mi] = *(const short8*)&As[(wm + mi * 16 + fr) * 32 + fq * 8];
#pragma unroll
        for (int ni = 0; ni < 4; ++ni)
            bfr[ni] = *(const short8*)&Bs[(wn + ni * 16 + fr) * 32 + fq * 8];
#pragma unroll
        for (int mi = 0; mi < 4; ++mi)
#pragma unroll
            for (int ni = 0; ni < 4; ++ni)
                acc[mi][ni] = __builtin_amdgcn_mfma_f32_16x16x32_bf16(
                    af[mi], bfr[ni], acc[mi][ni], 0, 0, 0);
        __syncthreads();
    }

    const bool relu = flags & 1;
    const bool obf  = flags & 2;
    const bool gate = flags & 4;
    const bool cmp  = flags & 8;
    const bool rbf  = flags & 16;
#pragma unroll
    for (int mi = 0; mi < 4; ++mi) {
#pragma unroll
        for (int ni = 0; ni < 4; ++ni) {
#pragma unroll
            for (int r = 0; r < 4; ++r) {
                int m = bm + wm + mi * 16 + fq * 4 + r;
                int n = bn + wn + ni * 16 + fr;
                float v = acc[mi][ni][r];
                if (n < N_real) {
                    v += bias[n];
                    if (relu) v = fmaxf(v, 0.f);
                    if (res) {
                        if (rbf)
                            v += __bfloat162float(
                                ((const __hip_bfloat16*)res)[(size_t)m * res_ld + n]);
                        else
                            v += ((const float*)res)[(size_t)m * res_ld + n];
                    }
                } else {
                    v = 0.f;
                }
                if (gate) {
                    ((float*)Cout)[(size_t)m * 512 + ((n & 127) << 2)
                                   + ((n >> 7) & 3) + (size_t)(n >> 9) * half_stride] = v;
                } else if (cmp) {
                    if (n < N_real)
                        ((float*)Cout)[(size_t)m * N_real + n] = v;
                } else if (obf) {
                    ((__hip_bfloat16*)Cout)[(size_t)m * Np + n] = __float2bfloat16(v);
                } else {
                    ((float*)Cout)[(size_t)m * Np + n] = v;
                }
            }
        }
    }
}

// ---------------------------------------------------------------------------
// Batched MFMA LSTM recurrence, 16 blocks x 512 threads (8 waves = 2/SIMD),
// 1 h per lane, NO duplication. Block = (dir, 4-sample group). Samples sit
// at LDS rows 4j: each lane's quad holds exactly one valid acc reg (r=0,
// sample = q); 8 waves cover the 128 hidden cols. Per-SIMD issue halves vs
// the 8-block config. Odd/non-4j rows stay zero (init once, never written).
__global__ __launch_bounds__(512, 4) void lstm_mfma_kernel(
    const float* __restrict__ pre_f, const float* __restrict__ pre_b,
    const __hip_bfloat16* __restrict__ whh_f,
    const __hip_bfloat16* __restrict__ whh_b,
    __hip_bfloat16* __restrict__ out)   // (B,S,2*LH) bf16
{
    const int dir = blockIdx.x >> 3;
    const int s0  = (blockIdx.x & 7) * 4;
    const float* pre = dir ? pre_b : pre_f;
    const __hip_bfloat16* whh = dir ? whh_b : whh_f;

    const int tid  = threadIdx.x;
    const int w8   = tid >> 6;          // 0..7 col group
    const int lane = tid & 63;
    const int l15  = lane & 15;
    const int q    = lane >> 4;         // sample within quad group
    const int col  = 16 * w8 + l15;
    const int lrow = 4 * q;             // LDS row = 4*sample

    short8 bf[4][4];
#pragma unroll
    for (int t = 0; t < 4; ++t) {
        const __hip_bfloat16* wrow = whh + (size_t)(t * 128 + col) * LH;
#pragma unroll
        for (int kt = 0; kt < 4; ++kt)
            bf[t][kt] = *(const short8*)(wrow + kt * 32 + q * 8);
    }

    __shared__ __hip_bfloat16 h_lds[2][16][136];
    for (int i = tid; i < 2 * 16 * 136; i += 512)
        ((__hip_bfloat16*)h_lds)[i] = __float2bfloat16(0.f);

    float c0 = 0.f;

    const int t0 = dir ? (S - 1) : 0;
    const int stepoff = dir ? -G4 : G4;
    const int outoff  = dir ? -256 : 256;
    const int row0 = s0 + q;            // global sample row 0..31

    const float* pp0 = pre + ((size_t)row0 * S + t0) * G4 + col * 4;
    __hip_bfloat16* op0 = out + ((size_t)row0 * S + t0) * 256 + dir * 128 + col;

    float4 pcA = *(const float4*)pp0; pp0 += stepoff;

    auto body = [&](const __hip_bfloat16 (&rb)[16][136],
                    __hip_bfloat16 (&wb)[16][136],
                    const float4& g0) {
        short8 af[4];
#pragma unroll
        for (int kt = 0; kt < 4; ++kt)
            af[kt] = *(const short8*)&rb[l15][kt * 32 + q * 8];

        f32x4 acc[4];
#pragma unroll
        for (int t = 0; t < 4; ++t) {
            acc[t] = (f32x4){0.f, 0.f, 0.f, 0.f};
#pragma unroll
            for (int kt = 0; kt < 4; ++kt)
                acc[t] = __builtin_amdgcn_mfma_f32_16x16x32_bf16(
                    af[kt], bf[t][kt], acc[t], 0, 0, 0);
        }

        // sample = q lives at C row 4q -> reg 0 of this lane's quad
        float Ei = e2(acc[0][0] + g0.x);
        float Ef = e2(acc[1][0] + g0.y);
        float Eg = e2(fminf(acc[2][0] + g0.z, 80.f));
        float Eo = e2(acc[3][0] + g0.w);
        float T  = (Eg - 1.f) * frcp((1.f + Ei) * (Eg + 1.f));
        c0 = fmaf(c0, frcp(1.f + Ef), T);
        float E2 = e2(fminf(c0 * (2.f * L2E), 80.f));
        float h0 = (E2 - 1.f) * frcp((1.f + Eo) * (E2 + 1.f));

        __hip_bfloat16 hb0 = __float2bfloat16(h0);
        wb[lrow][col] = hb0;
        *op0 = hb0; op0 += outoff;
    };

    barrier_lds();

    for (int it = 0; it < S / 2; ++it) {
        float4 pcB = *(const float4*)pp0; pp0 += stepoff;
        body(h_lds[0], h_lds[1], pcA);
        barrier_lds();
        pcA = *(const float4*)pp0; pp0 += stepoff;
        body(h_lds[1], h_lds[0], pcB);
        barrier_lds();
    }
}

// ---------------------------------------------------------------------------
// CRF NLL per sample (round-10 version: __syncthreads + em/mask prefetch)
__global__ __launch_bounds__(64) void crf_kernel(
    const float* __restrict__ em, const int* __restrict__ labels,
    const int* __restrict__ mask, const float* __restrict__ trans,
    float* __restrict__ nll)
{
    int b = blockIdx.x, tid = threadIdx.x;
    __shared__ float tr[NT * NT];
    __shared__ float alpha[NT];
    __shared__ float red[64];
    __shared__ float gold_s;

    for (int i = tid; i < NT * NT; i += 64) tr[i] = trans[i];
    __syncthreads();

    float emit = 0.f, pair = 0.f, lenf = 0.f;
    for (int s = tid; s < S; s += 64) {
        int lab = labels[b * S + s];
        float mf = (float)mask[b * S + s];
        emit += em[(size_t)(b * S + s) * NT + lab] * mf;
        lenf += mf;
        if (s >= 1) {
            int lp = labels[b * S + s - 1];
            pair += tr[lp * NT + lab] * mf;
        }
    }
    red[tid] = emit; __syncthreads();
    for (int st = 32; st > 0; st >>= 1) { if (tid < st) red[tid] += red[tid + st]; __syncthreads(); }
    float emit_tot = red[0]; __syncthreads();
    red[tid] = pair; __syncthreads();
    for (int st = 32; st > 0; st >>= 1) { if (tid < st) red[tid] += red[tid + st]; __syncthreads(); }
    float pair_tot = red[0]; __syncthreads();
    red[tid] = lenf; __syncthreads();
    for (int st = 32; st > 0; st >>= 1) { if (tid < st) red[tid] += red[tid + st]; __syncthreads(); }
    float len_tot = red[0]; __syncthreads();

    if (tid == 0) {
        int len_i = (int)(len_tot + 0.5f);
        int last = labels[b * S + len_i - 1];
        gold_s = tr[START_TAG * NT + labels[b * S]] + emit_tot + pair_tot
               + tr[last * NT + END_TAG];
    }
    if (tid < NT) alpha[tid] = tr[START_TAG * NT + tid] + em[(size_t)(b * S) * NT + tid];
    __syncthreads();

    float ecur = (tid < NT) ? em[(size_t)(b * S + 1) * NT + tid] : 0.f;
    int   mcur = mask[b * S + 1];

    for (int t = 1; t < S; ++t) {
        float enxt = 0.f; int mnxt = 0;
        if (t + 1 < S) {
            if (tid < NT) enxt = em[(size_t)(b * S + t + 1) * NT + tid];
            mnxt = mask[b * S + t + 1];
        }
        float newv = 0.f;
        if (tid < NT) {
            float vals[NT];
            float m = -1e30f;
#pragma unroll
            for (int i2 = 0; i2 < NT; ++i2) {
                float v = alpha[i2] + tr[i2 * NT + tid];
                vals[i2] = v;
                m = fmaxf(m, v);
            }
            float ssum = 0.f;
#pragma unroll
            for (int i2 = 0; i2 < NT; ++i2) ssum += __expf(vals[i2] - m);
            newv = m + __logf(ssum) + ecur;
            if (!(mcur > 0)) newv = alpha[tid];
        }
        __syncthreads();
        if (tid < NT) alpha[tid] = newv;
        __syncthreads();
        ecur = enxt; mcur = mnxt;
    }

    if (tid < NT) red[tid] = alpha[tid] + tr[tid * NT + END_TAG];
    __syncthreads();
    if (tid == 0) {
        float m = -1e30f;
        for (int j = 0; j < NT; ++j) m = fmaxf(m, red[j]);
        float ssum = 0.f;
        for (int j = 0; j < NT; ++j) ssum += __expf(red[j] - m);
        float logZ = m + __logf(ssum);
        nll[b] = logZ - gold_s;
    }
}

__global__ void mean_kernel(const float* __restrict__ nll, float* __restrict__ out)
{
    if (threadIdx.x == 0) {
        float s = 0.f;
        for (int i = 0; i < B; ++i) s += nll[i];
        out[0] = s / (float)B;
    }
}

// ---------------------------------------------------------------------------
extern "C" void kernel_launch(void* const* d_in, const int* in_sizes, int n_in,
                              void* d_out, int out_size, void* d_ws, size_t ws_size,
                              hipStream_t stream)
{
    const float* in_emb = (const float*)d_in[0];
    const int*   mask   = (const int*)d_in[1];
    const int*   labels = (const int*)d_in[2];
    const float* kg_W1  = (const float*)d_in[3];
    const float* kg_b1  = (const float*)d_in[4];
    const float* ln_g   = (const float*)d_in[5];
    const float* ln_b   = (const float*)d_in[6];
    const float* kg_W2  = (const float*)d_in[7];
    const float* kg_b2  = (const float*)d_in[8];
    const float* ff_W1  = (const float*)d_in[9];
    const float* ff_b1  = (const float*)d_in[10];
    const float* ff_W2  = (const float*)d_in[11];
    const float* ff_b2  = (const float*)d_in[12];
    const float* Wih0f  = (const float*)d_in[13];
    const float* Whh0f  = (const float*)d_in[14];
    const float* b0f    = (const float*)d_in[15];
    const float* Wih0b  = (const float*)d_in[16];
    const float* Whh0b  = (const float*)d_in[17];
    const float* b0b    = (const float*)d_in[18];
    const float* Wih1f  = (const float*)d_in[19];
    const float* Whh1f  = (const float*)d_in[20];
    const float* b1f    = (const float*)d_in[21];
    const float* Wih1b  = (const float*)d_in[22];
    const float* Whh1b  = (const float*)d_in[23];
    const float* b1b    = (const float*)d_in[24];
    const float* cls_W  = (const float*)d_in[25];
    const float* cls_b  = (const float*)d_in[26];
    const float* trans  = (const float*)d_in[27];
    (void)ws_size; (void)in_sizes; (void)n_in; (void)out_size;

    // ---- workspace arena ----
    char* wsb = (char*)d_ws;
    size_t o = 0;
    __hip_bfloat16* Ab     = (__hip_bfloat16*)(wsb + o);   size_t ab_off = o; o += (size_t)M_TOK * DP * 2;
    char*           big    = wsb + o;                      o += (size_t)M_TOK * FF * 2;
    __hip_bfloat16* xb     = (__hip_bfloat16*)(wsb + o);   o += (size_t)M_TOK * DP * 2;
    __hip_bfloat16* Wbff1  = (__hip_bfloat16*)(wsb + o);   o += (size_t)FF * DP * 2;
    __hip_bfloat16* Wbff2  = (__hip_bfloat16*)(wsb + o);   o += (size_t)DP * FF * 2;
    __hip_bfloat16* Wb0    = (__hip_bfloat16*)(wsb + o);   o += (size_t)1024 * DP * 2;
    __hip_bfloat16* Wb1    = (__hip_bfloat16*)(wsb + o);   o += (size_t)1024 * 256 * 2;
    __hip_bfloat16* Whb0f  = (__hip_bfloat16*)(wsb + o);   o += (size_t)G4 * LH * 2;
    __hip_bfloat16* Whb0b  = (__hip_bfloat16*)(wsb + o);   o += (size_t)G4 * LH * 2;
    __hip_bfloat16* Whb1f  = (__hip_bfloat16*)(wsb + o);   o += (size_t)G4 * LH * 2;
    __hip_bfloat16* Whb1b  = (__hip_bfloat16*)(wsb + o);   o += (size_t)G4 * LH * 2;
    __hip_bfloat16* Wbkg1  = (__hip_bfloat16*)(wsb + o);   o += (size_t)H * KGP * 2;
    __hip_bfloat16* Wbcls  = (__hip_bfloat16*)(wsb + o);   o += (size_t)128 * 256 * 2;
    float*          sb0    = (float*)(wsb + o);            o += 1024 * 4;
    float*          sb1    = (float*)(wsb + o);            o += 1024 * 4;
    float*          scores = (float*)(wsb + o);            o += (size_t)M_TOK * 4;
    float*          attw   = (float*)(wsb + o);            o += (size_t)M_TOK * 4;
    float*          emis   = (float*)(wsb + o);            o += (size_t)M_TOK * NT * 4;
    float*          nll    = (float*)(wsb + o);            o += B * 4;
    // big region reuse timeline:
    __hip_bfloat16* h16   = (__hip_bfloat16*)(big + 0);
    __hip_bfloat16* Akg   = (__hip_bfloat16*)(big + 33554432);
    __hip_bfloat16* ff1b  = (__hip_bfloat16*)big;
    float*          pre0f = (float*)(big + 0);
    float*          pre0b = (float*)(big + 16777216);
    __hip_bfloat16* x1b   = (__hip_bfloat16*)(big + 33554432);
    float*          pre1f = (float*)(big + 0);
    float*          pre1b = (float*)(big + 16777216);
    __hip_bfloat16* x2b   = (__hip_bfloat16*)(wsb + ab_off);
    const size_t HALF_STRIDE = 4194304;   // floats: pre0f -> pre0b

    // ---- all weight prep in ONE launch ----
    prep_all_kernel<<<(PREP_TOTAL + 255) / 256, 256, 0, stream>>>(
        ff_W1, ff_W2, Wih0f, Wih0b, Wih1f, Wih1b,
        Whh0f, Whh0b, Whh1f, Whh1b, b0f, b0b, b1f, b1b, cls_W, kg_W1,
        Wbff1, Wbff2, Wb0, Wb1, Whb0f, Whb0b, Whb1f, Whb1b,
        sb0, sb1, Wbcls, Wbkg1);

    // ---- attention front-end ----
    castpad_kg_kernel<<<(M_TOK * KGP + 255) / 256, 256, 0, stream>>>(in_emb, Akg);
    mfma_gemm<<<dim3(H / 128, M_TOK / 128), 256, 0, stream>>>(
        Akg, Wbkg1, kg_b1, nullptr, 0, 0, h16, H, KGP, H, 2);
    ln_score_kernel<<<M_TOK / 4, 256, 0, stream>>>(
        h16, ln_g, ln_b, kg_W2, kg_b2, scores);
    softmax_kernel<<<B, 256, 0, stream>>>(scores, attw);
    combine2_kernel<<<(M_TOK * DP + 255) / 256, 256, 0, stream>>>(in_emb, attw, Ab);

    // ---- FF block ----
    mfma_gemm<<<dim3(FF / 128, M_TOK / 128), 256, 0, stream>>>(
        Ab, Wbff1, ff_b1, nullptr, 0, 0, ff1b, FF, DP, FF, 1 | 2);
    mfma_gemm<<<dim3(DP / 128, M_TOK / 128), 256, 0, stream>>>(
        ff1b, Wbff2, ff_b2, Ab, DP, 0, xb, DP, FF, D, 2 | 16);

    // ---- LSTM layer 0 ----
    mfma_gemm<<<dim3(1024 / 128, M_TOK / 128), 256, 0, stream>>>(
        xb, Wb0, sb0, nullptr, 0, HALF_STRIDE, pre0f, 1024, DP, 1024, 4);
    lstm_mfma_kernel<<<16, 512, 0, stream>>>(pre0f, pre0b, Whb0f, Whb0b, x1b);

    // ---- LSTM layer 1 ----
    mfma_gemm<<<dim3(1024 / 128, M_TOK / 128), 256, 0, stream>>>(
        x1b, Wb1, sb1, nullptr, 0, HALF_STRIDE, pre1f, 1024, 256, 1024, 4);
    lstm_mfma_kernel<<<16, 512, 0, stream>>>(pre1f, pre1b, Whb1f, Whb1b, x2b);

    // ---- emissions + CRF + mean ----
    mfma_gemm<<<dim3(1, M_TOK / 128), 256, 0, stream>>>(
        x2b, Wbcls, cls_b, nullptr, 0, 0, emis, 128, 256, NT, 8);
    crf_kernel<<<B, 64, 0, stream>>>(emis, labels, mask, trans, nll);
    mean_kernel<<<1, 64, 0, stream>>>(nll, (float*)d_out);
}